// Round 8
// baseline (60.536 us; speedup 1.0000x reference)
//
#include <hip/hip_runtime.h>

// Problem constants (match reference)
#define XD 256
#define YD 256
#define ZD 16
#define TD 5
#define BD 2
#define NP 300000
#define CMID 8
#define VPB (XD * YD * ZD * TD)        // 5,242,880 voxels per batch
#define NVOX (BD * VPB)                // 10,485,760 total voxels
#define MAXPTS (BD * NP)               // 600,000
// Occupancy layout: 8 bits per (b,x,y,z) cell (t occupies bits 0..4).
// idx8 = (b<<23)|(x<<15)|(y<<7)|(z<<3)|t  -> all power-of-2 decode.
#define OCC_BYTES (BD * XD * YD * ZD)  // 2 MiB (L2-resident)
#define OCC_U128  (OCC_BYTES / 16)     // 131,072 16B columns

#define SCAT_BLOCKS ((MAXPTS + 255) / 256)   // 2344
#define CONV_BLOCKS 2048               // 131,072 columns / 64 per block
#define STRIP 5120                     // 64 cols * 80 floats of output per block

// ---------------------------------------------------------------------------
// Kernel 0: zero the 2 MiB occupancy bitfield (one uint4 store per thread).
// ---------------------------------------------------------------------------
__global__ __launch_bounds__(256) void zero_occ_kernel(uint4* __restrict__ occ) {
    int i = blockIdx.x * 256 + threadIdx.x;   // grid = 512 blocks -> exactly OCC_U128
    uint4 z = {0u, 0u, 0u, 0u};
    occ[i] = z;
}

// ---------------------------------------------------------------------------
// Kernel 1: scatter points -> occupancy bits (idempotent atomicOr).
// ---------------------------------------------------------------------------
__global__ __launch_bounds__(256) void scatter_kernel(
    const float4* __restrict__ pts, unsigned int* __restrict__ occ) {
    int i = blockIdx.x * 256 + threadIdx.x;
    if (i >= MAXPTS) return;
    float4 p = pts[i];
    // Match JAX exactly: floor(p / quant) (fp32 division), then clip.
    int cx = min(max((int)floorf(p.x / 0.4f), 0), XD - 1);
    int cy = min(max((int)floorf(p.y / 0.4f), 0), YD - 1);
    int cz = min(max((int)floorf(p.z / 0.4f), 0), ZD - 1);
    int ct = min(max((int)floorf(p.w / 1.0f), 0), TD - 1);
    int b  = i / NP;
    unsigned idx8 = ((unsigned)b << 23) | ((unsigned)cx << 15) |
                    ((unsigned)cy << 7) | ((unsigned)cz << 3) | (unsigned)ct;
    atomicOr(&occ[idx8 >> 5], 1u << (idx8 & 31));
}

// ---------------------------------------------------------------------------
// Kernel 2: strip-local conv; block owns columns (b, x, ny0..ny0+63) and is
// the SOLE writer of its 20 KB output strip:
//   1. zero a 20 KB LDS out-tile; coalesced-load 3x66 neighbor columns
//   2. block-local compaction (shfl wave-scan, 2 barriers, no atomics)
//   3. per-entry m-table conv + ReLU + 8->1 proj -> scatter into LDS out-tile
//   4. dense coalesced float4 store of the whole strip (full lines, no
//      write-allocate refetch; replaces the separate 42 MB zero pass)
// ---------------------------------------------------------------------------
__global__ __launch_bounds__(256) void conv_kernel(
    const ulonglong2* __restrict__ occ128,  // 16B z-column per (b,x,y)
    const float* __restrict__ W0,   // (81, 1, 8)
    const float* __restrict__ b0,   // (8)
    const float* __restrict__ W1,   // (8, 1)
    const float* __restrict__ b1,   // (1)
    float4* __restrict__ out4) {
    __shared__ float tab[216 * 12];
    __shared__ ulonglong2 cols[3][66];
    __shared__ unsigned short queue[STRIP];
    __shared__ float outt[STRIP];
    __shared__ unsigned wsum[4];
    __shared__ float b0s[CMID];
    __shared__ float w1s[CMID];
    __shared__ float b1s;

    int tid = threadIdx.x;
    int blk = blockIdx.x;
    int b   = blk >> 10;
    int x   = (blk >> 2) & 255;
    int ny0 = (blk & 3) << 6;

    // --- zero the LDS out-tile (1280 float4 = 5 per thread) ---
    float4* ot4 = (float4*)outt;
    float4 zf = {0.f, 0.f, 0.f, 0.f};
#pragma unroll
    for (int j = 0; j < 5; ++j) ot4[tid + j * 256] = zf;

    // --- mask-table: entry e = kb[0,27) * 8 + m[0,8); rows padded to 12 ---
    for (int e = tid; e < 216; e += 256) {
        int kb = e >> 3;
        int m  = e & 7;
        float acc[CMID];
#pragma unroll
        for (int c = 0; c < CMID; ++c) acc[c] = 0.0f;
#pragma unroll
        for (int dti = 0; dti < 3; ++dti) {
            if ((m >> dti) & 1) {
                const float* w = &W0[(kb * 3 + dti) * CMID];
#pragma unroll
                for (int c = 0; c < CMID; ++c) acc[c] += w[c];
            }
        }
#pragma unroll
        for (int c = 0; c < CMID; ++c) tab[e * 12 + c] = acc[c];
    }
    if (tid < CMID) {
        b0s[tid] = b0[tid];
        w1s[tid] = W1[tid];
    }
    if (tid == 0) b1s = b1[0];

    // --- coalesced load of the 3x66 column neighborhood ---
    for (int j = tid; j < 3 * 66; j += 256) {
        int r   = j / 66;           // dxi
        int cyl = j % 66;           // local ny + 1
        int nx  = x + r - 1;
        int cy  = ny0 + cyl - 1;
        bool valid = ((unsigned)nx < XD) && ((unsigned)cy < YD);
        ulonglong2 col = occ128[(b << 16) | ((nx & 255) << 8) | (cy & 255)];
        ulonglong2 v;
        v.x = valid ? col.x : 0ull;
        v.y = valid ? col.y : 0ull;
        cols[r][cyl] = v;
    }
    __syncthreads();

    // --- block-local compaction: word tid of own 64 columns ---
    const unsigned* ownw = (const unsigned*)&cols[1][1];   // 256 contiguous u32
    unsigned w = ownw[tid];
    int cnt = __popc(w);

    // Inclusive wave-prefix via shfl_up (no barriers), then cross-wave fixup.
    unsigned pre = (unsigned)cnt;
#pragma unroll
    for (int off = 1; off < 64; off <<= 1) {
        unsigned v = (unsigned)__shfl_up((int)pre, off, 64);
        if ((tid & 63) >= off) pre += v;
    }
    int wv = tid >> 6;
    if ((tid & 63) == 63) wsum[wv] = pre;
    __syncthreads();
    unsigned base = 0;
#pragma unroll
    for (int k = 0; k < 4; ++k) base += (k < wv) ? wsum[k] : 0u;
    unsigned qlen = wsum[0] + wsum[1] + wsum[2] + wsum[3];
    unsigned pos  = base + pre - (unsigned)cnt;   // exclusive prefix

    {
        int cl = tid >> 2;          // column-in-block
        int zb = (tid & 3) << 2;    // z base of this word
        unsigned ww = w;
        while (ww) {
            int bi = __ffs(ww) - 1;
            ww &= ww - 1;
            int zz = zb + (bi >> 3);
            int tt = bi & 7;        // always < 5 (scatter sets only t<5)
            queue[pos++] = (unsigned short)((cl << 7) | (zz << 3) | tt);
        }
    }
    __syncthreads();

    // --- conv over compacted entries -> LDS out-tile ---
    for (unsigned q = tid; q < qlen; q += 256) {
        int e  = queue[q];
        int cl = e >> 7;
        int z  = (e >> 3) & 15;
        int t  = e & 7;

        float4 h0 = {0.f, 0.f, 0.f, 0.f};
        float4 h1 = {0.f, 0.f, 0.f, 0.f};
#pragma unroll
        for (int dxi = 0; dxi < 3; ++dxi) {
#pragma unroll
            for (int dyi = 0; dyi < 3; ++dyi) {
                ulonglong2 col = cols[dxi][cl + dyi];   // LDS b128 read
                int p3 = (dxi * 3 + dyi) * 3;
#pragma unroll
                for (int dzi = 0; dzi < 3; ++dzi) {
                    int nz = z + dzi - 1;                     // in [-1, 16]
                    unsigned sh = ((unsigned)nz * 8u) & 63u;  // wrap-safe
                    unsigned r = (unsigned)(((nz & 8) ? (col.y >> sh)
                                                      : (col.x >> sh)) & 0xffull);
                    r = ((unsigned)nz < ZD) ? r : 0u;
                    unsigned m = ((r << 1) >> t) & 7u;  // bits t-1,t,t+1
                    if (m) {                            // ~16% of taps fire
                        const float4* row =
                            (const float4*)&tab[((p3 + dzi) * 8 + (int)m) * 12];
                        h0 += row[0];
                        h1 += row[1];
                    }
                }
            }
        }

        float hc[CMID] = {h0.x, h0.y, h0.z, h0.w, h1.x, h1.y, h1.z, h1.w};
        float o = 0.0f;
#pragma unroll
        for (int c = 0; c < CMID; ++c) {
            float v = 0.5f * hc[c] + b0s[c];   // grid value is exactly 0.5
            v = v > 0.0f ? v : 0.0f;           // relu
            o += v * w1s[c];
        }
        outt[cl * 80 + z * 5 + t] = o + b1s;
    }
    __syncthreads();

    // --- dense coalesced store of the whole strip (sole writer) ---
    const float4* src = (const float4*)outt;
    float4* dst = out4 + ((size_t)b * (VPB / 4)) + (size_t)(x * YD + ny0) * 20;
#pragma unroll
    for (int j = 0; j < 5; ++j) dst[tid + j * 256] = src[tid + j * 256];
}

extern "C" void kernel_launch(void* const* d_in, const int* in_sizes, int n_in,
                              void* d_out, int out_size, void* d_ws, size_t ws_size,
                              hipStream_t stream) {
    const float4* pts = (const float4*)d_in[0];
    const float* W0   = (const float*)d_in[1];
    const float* b0   = (const float*)d_in[2];
    const float* W1   = (const float*)d_in[3];
    const float* b1   = (const float*)d_in[4];
    float* out = (float*)d_out;
    unsigned int* occ = (unsigned int*)d_ws;   // 2 MiB bitfield

    zero_occ_kernel<<<OCC_U128 / 256, 256, 0, stream>>>((uint4*)occ);
    scatter_kernel<<<SCAT_BLOCKS, 256, 0, stream>>>(pts, occ);
    conv_kernel<<<CONV_BLOCKS, 256, 0, stream>>>(
        (const ulonglong2*)occ, W0, b0, W1, b1, (float4*)out);
}